// Round 5
// baseline (27.071 us; speedup 1.0000x reference)
//
#include <hip/hip_runtime.h>

#define VOCAB 1024
#define ARCS  16
#define MAX_ORDER 4
#define CHAIN (MAX_ORDER - 1)
#define START_STATE 0
#define WAVE 64
#define HYP_PER_BLOCK 4
#define BLOCK (WAVE * HYP_PER_BLOCK)

typedef float f32x4 __attribute__((ext_vector_type(4)));
typedef int   i32x4 __attribute__((ext_vector_type(4)));

// 256-thread block = 4 independent waves, one hypothesis per wave. Zero LDS.
// Priority resolved in registers (readlane dedup); overlay applied as a
// fenced global scatter after the dense stores.
__global__ __launch_bounds__(BLOCK, 8) void ngram_advance_kernel(
    const float* __restrict__ arcs_weights,
    const float* __restrict__ backoff_weights,
    const int*   __restrict__ ilabels,
    const int*   __restrict__ to_states,
    const int*   __restrict__ backoff_to,
    const int*   __restrict__ state_start,
    const int*   __restrict__ state_end,
    const int*   __restrict__ states,
    float*       __restrict__ out_scores,   // [B, V]
    float*       __restrict__ out_next)     // [B, V] state ids as f32
{
    const int lane = threadIdx.x & (WAVE - 1);
    // wave-uniform hypothesis id, forced scalar so the chain walk s_loads
    const int b = __builtin_amdgcn_readfirstlane(
        blockIdx.x * HYP_PER_BLOCK + (threadIdx.x >> 6));

    // Kick off the longest dependency chain first (scalar load).
    int cur = states[b];

    float* __restrict__ so = out_scores + (size_t)b * VOCAB;
    float* __restrict__ no = out_next   + (size_t)b * VOCAB;

    // ---- Dense next-states: depends on NOTHING — issue these 16 KB of
    // stores immediately so the chain-walk latency hides under write drain.
    #pragma unroll
    for (int i = 0; i < VOCAB / (WAVE * 4); ++i) {
        const int v = (lane + i * WAVE) * 4;
        const i32x4 dn = *(const i32x4*)&to_states[v];   // L1-hot table
        f32x4 rn;
        rn.x = (float)dn.x;  rn.y = (float)dn.y;
        rn.z = (float)dn.z;  rn.w = (float)dn.w;
        __builtin_nontemporal_store(rn, (f32x4*)&no[v]);
    }

    // ---- Chain walk (scalar, uniform). ----
    float acc = 0.0f;
    const int   cs0 = cur;  const float ca0 = acc;
    if (cur != START_STATE) { acc += backoff_weights[cur]; cur = backoff_to[cur]; }
    const int   cs1 = cur;  const float ca1 = acc;
    if (cur != START_STATE) { acc += backoff_weights[cur]; cur = backoff_to[cur]; }
    const int   cs2 = cur;  const float ca2 = acc;
    if (cur != START_STATE) { acc += backoff_weights[cur]; }
    const float accf = acc;

    // ---- Parallel arc fetch: lanes 0..47, level = lane>>4, arc = lane&15 ----
    const int level = lane >> 4;
    const int arc   = lane & (ARCS - 1);
    int   lab = -1, ns = 0;
    float sc  = 0.0f;
    bool  ok  = false;
    if (lane < CHAIN * ARCS) {
        const int   s    = (level == 0) ? cs0 : ((level == 1) ? cs1 : cs2);
        const float cacc = (level == 0) ? ca0 : ((level == 1) ? ca1 : ca2);
        if (s != START_STATE) {
            const int idx = state_start[s] + arc;
            if (idx < state_end[s]) {
                lab = ilabels[idx];
                sc  = cacc + arcs_weights[idx];
                ns  = to_states[idx];
                ok  = true;
            }
        }
    }

    // ---- Dense scores (needs accf); overlaps the in-flight arc loads. ----
    #pragma unroll
    for (int i = 0; i < VOCAB / (WAVE * 4); ++i) {
        const int v = (lane + i * WAVE) * 4;
        const f32x4 dw = *(const f32x4*)&arcs_weights[v];  // L1-hot table
        f32x4 rs;
        rs.x = accf + dw.x;  rs.y = accf + dw.y;
        rs.z = accf + dw.z;  rs.w = accf + dw.w;
        __builtin_nontemporal_store(rs, (f32x4*)&so[v]);
    }

    // ---- In-register dedup: kill a lane if a LOWER level (higher n-gram
    // order, higher priority) holds the same label. Invalid lanes carry
    // lab = -1 which never matches a real label.
    int kill = 0;
    #pragma unroll
    for (int k = 0; k < 2 * ARCS; ++k) {
        const int lk = __builtin_amdgcn_readlane(lab, k);
        if (k < ARCS) kill |= (int)(level >= 1) & (int)(lab == lk);
        else          kill |= (int)(level == 2) & (int)(lab == lk);
    }
    const bool do_scatter = ok && !kill;

    // ---- Fence: dense stores reach the coherency point before the overlay
    // scatter, so the scatter wins the same-address race. ----
    asm volatile("s_waitcnt vmcnt(0)" ::: "memory");

    if (do_scatter) {
        so[lab] = sc;
        no[lab] = (float)ns;
    }
}

extern "C" void kernel_launch(void* const* d_in, const int* in_sizes, int n_in,
                              void* d_out, int out_size, void* d_ws, size_t ws_size,
                              hipStream_t stream) {
    const float* arcs_weights    = (const float*)d_in[0];
    const float* backoff_weights = (const float*)d_in[1];
    const int*   ilabels         = (const int*)d_in[2];
    const int*   to_states       = (const int*)d_in[3];
    const int*   backoff_to      = (const int*)d_in[4];
    const int*   state_start     = (const int*)d_in[5];
    const int*   state_end       = (const int*)d_in[6];
    const int*   states          = (const int*)d_in[7];

    const int B = in_sizes[7];                           // 8192 hypotheses
    float* out_scores = (float*)d_out;                   // first B*V floats
    float* out_next   = out_scores + (size_t)B * VOCAB;  // second B*V

    ngram_advance_kernel<<<B / HYP_PER_BLOCK, BLOCK, 0, stream>>>(
        arcs_weights, backoff_weights, ilabels, to_states, backoff_to,
        state_start, state_end, states, out_scores, out_next);
}

// Round 6
// 24.585 us; speedup vs baseline: 1.1011x; 1.1011x over previous
//
#include <hip/hip_runtime.h>

#define VOCAB 1024
#define ARCS  16
#define CHAIN 3
#define START_STATE 0
#define WAVE 64
#define HYP_PER_WAVE 4
#define WAVES_PER_BLOCK 4
#define BLOCK (WAVE * WAVES_PER_BLOCK)
#define HYP_PER_BLOCK (HYP_PER_WAVE * WAVES_PER_BLOCK)
#define NCHUNK (VOCAB / (WAVE * 4))   // 4 x 16B chunks per thread

typedef float f32x4 __attribute__((ext_vector_type(4)));
typedef int   i32x4 __attribute__((ext_vector_type(4)));

// 4 waves/block, 4 hypotheses/wave. Zero LDS. Chain walks for the 4 hyps are
// independent scalar chains -> their latency rounds overlap; dense tables are
// loaded once per wave and stored 4x. Priority resolved in registers
// (readlane dedup); overlay applied as a fenced global scatter (normal
// stores -> scatter hits the L2 lines the dense stores populated).
__global__ __launch_bounds__(BLOCK, 2) void ngram_advance_kernel(
    const float* __restrict__ arcs_weights,
    const float* __restrict__ backoff_weights,
    const int*   __restrict__ ilabels,
    const int*   __restrict__ to_states,
    const int*   __restrict__ backoff_to,
    const int*   __restrict__ state_start,
    const int*   __restrict__ state_end,
    const int*   __restrict__ states,
    float*       __restrict__ out_scores,   // [B, V]
    float*       __restrict__ out_next,     // [B, V] state ids as f32
    int B)
{
    const int lane = threadIdx.x & (WAVE - 1);
    const int wid  = __builtin_amdgcn_readfirstlane(threadIdx.x >> 6);
    const int b0   = blockIdx.x * HYP_PER_BLOCK + wid * HYP_PER_WAVE;

    // ---- 1. Kick off the 4 independent chain heads (scalar loads). ----
    int cur[HYP_PER_WAVE];
    #pragma unroll
    for (int h = 0; h < HYP_PER_WAVE; ++h) {
        int bb = b0 + h;
        bb = bb < B ? bb : B - 1;          // clamp loads; stores guarded below
        cur[h] = states[bb];
    }

    // ---- 2. Dense next-state half: table loaded/converted ONCE, stored 4x.
    // Depends on nothing -> these stores fill the chain-walk latency bubble.
    f32x4 rn[NCHUNK];
    #pragma unroll
    for (int i = 0; i < NCHUNK; ++i) {
        const i32x4 dn = *(const i32x4*)&to_states[(lane + i * WAVE) * 4];
        rn[i].x = (float)dn.x; rn[i].y = (float)dn.y;
        rn[i].z = (float)dn.z; rn[i].w = (float)dn.w;
    }
    #pragma unroll
    for (int h = 0; h < HYP_PER_WAVE; ++h) {
        const int b = b0 + h;
        if (b < B) {
            float* __restrict__ no = out_next + (size_t)b * VOCAB;
            #pragma unroll
            for (int i = 0; i < NCHUNK; ++i)
                *(f32x4*)&no[(lane + i * WAVE) * 4] = rn[i];
        }
    }

    // ---- 3. Chain walks, branchless (backoff_weights[0]==0 and
    // backoff_to[0]==0: START self-loops at zero cost). 4 independent
    // chains -> each of the 3 rounds issues 8 parallel scalar loads.
    int   cs[HYP_PER_WAVE][CHAIN];
    float ca[HYP_PER_WAVE][CHAIN];
    float acc[HYP_PER_WAVE];
    #pragma unroll
    for (int h = 0; h < HYP_PER_WAVE; ++h) acc[h] = 0.0f;
    #pragma unroll
    for (int t = 0; t < CHAIN; ++t) {
        #pragma unroll
        for (int h = 0; h < HYP_PER_WAVE; ++h) {
            cs[h][t] = cur[h];
            ca[h][t] = acc[h];             // acc BEFORE this state's backoff
            acc[h]  += backoff_weights[cur[h]];
            cur[h]   = backoff_to[cur[h]];
        }
    }
    // acc[h] is now the fully-backed-off accumulator (accf).

    // ---- 4. Arc fetch: lanes 0..47, level = lane>>4, arc = lane&15. ----
    const int level = lane >> 4;
    const int arc   = lane & (ARCS - 1);
    int   lab[HYP_PER_WAVE], ns[HYP_PER_WAVE];
    float sc[HYP_PER_WAVE];
    bool  ok[HYP_PER_WAVE];
    #pragma unroll
    for (int h = 0; h < HYP_PER_WAVE; ++h) {
        lab[h] = -1; ns[h] = 0; sc[h] = 0.0f; ok[h] = false;
        if (lane < CHAIN * ARCS) {
            const int   s    = (level == 0) ? cs[h][0] : (level == 1) ? cs[h][1] : cs[h][2];
            const float cacc = (level == 0) ? ca[h][0] : (level == 1) ? ca[h][1] : ca[h][2];
            if (s != START_STATE) {
                const int idx = state_start[s] + arc;
                if (idx < state_end[s]) {
                    lab[h] = ilabels[idx];
                    sc[h]  = cacc + arcs_weights[idx];
                    ns[h]  = to_states[idx];
                    ok[h]  = true;
                }
            }
        }
    }

    // ---- 5. Dense scores half: table loaded ONCE, per-hyp accf added. ----
    f32x4 dw[NCHUNK];
    #pragma unroll
    for (int i = 0; i < NCHUNK; ++i)
        dw[i] = *(const f32x4*)&arcs_weights[(lane + i * WAVE) * 4];
    #pragma unroll
    for (int h = 0; h < HYP_PER_WAVE; ++h) {
        const int b = b0 + h;
        if (b < B) {
            float* __restrict__ so = out_scores + (size_t)b * VOCAB;
            const float a = acc[h];
            #pragma unroll
            for (int i = 0; i < NCHUNK; ++i) {
                f32x4 rs;
                rs.x = a + dw[i].x; rs.y = a + dw[i].y;
                rs.z = a + dw[i].z; rs.w = a + dw[i].w;
                *(f32x4*)&so[(lane + i * WAVE) * 4] = rs;
            }
        }
    }

    // ---- 6. In-register dedup: kill a lane if a LOWER level (higher
    // n-gram order = higher priority) holds the same label. Invalid lanes
    // carry lab = -1, which never matches a real label. ----
    int kill[HYP_PER_WAVE];
    #pragma unroll
    for (int h = 0; h < HYP_PER_WAVE; ++h) {
        kill[h] = 0;
        #pragma unroll
        for (int k = 0; k < 2 * ARCS; ++k) {
            const int lk = __builtin_amdgcn_readlane(lab[h], k);
            if (k < ARCS) kill[h] |= (int)(level >= 1) & (int)(lab[h] == lk);
            else          kill[h] |= (int)(level == 2) & (int)(lab[h] == lk);
        }
    }

    // ---- 7. Fence: dense stores reach the L2 coherency point before the
    // overlay scatter, so the scatter wins the same-address race. ----
    asm volatile("s_waitcnt vmcnt(0)" ::: "memory");

    // ---- 8. Overlay scatter (<=48 label-distinct entries per hyp). ----
    #pragma unroll
    for (int h = 0; h < HYP_PER_WAVE; ++h) {
        const int b = b0 + h;
        if (b < B && ok[h] && !kill[h]) {
            out_scores[(size_t)b * VOCAB + lab[h]] = sc[h];
            out_next  [(size_t)b * VOCAB + lab[h]] = (float)ns[h];
        }
    }
}

extern "C" void kernel_launch(void* const* d_in, const int* in_sizes, int n_in,
                              void* d_out, int out_size, void* d_ws, size_t ws_size,
                              hipStream_t stream) {
    const float* arcs_weights    = (const float*)d_in[0];
    const float* backoff_weights = (const float*)d_in[1];
    const int*   ilabels         = (const int*)d_in[2];
    const int*   to_states       = (const int*)d_in[3];
    const int*   backoff_to      = (const int*)d_in[4];
    const int*   state_start     = (const int*)d_in[5];
    const int*   state_end       = (const int*)d_in[6];
    const int*   states          = (const int*)d_in[7];

    const int B = in_sizes[7];                           // 8192 hypotheses
    float* out_scores = (float*)d_out;                   // first B*V floats
    float* out_next   = out_scores + (size_t)B * VOCAB;  // second B*V

    const int grid = (B + HYP_PER_BLOCK - 1) / HYP_PER_BLOCK;
    ngram_advance_kernel<<<grid, BLOCK, 0, stream>>>(
        arcs_weights, backoff_weights, ilabels, to_states, backoff_to,
        state_start, state_end, states, out_scores, out_next, B);
}

// Round 7
// 19.548 us; speedup vs baseline: 1.3849x; 1.2577x over previous
//
#include <hip/hip_runtime.h>

#define VOCAB 1024
#define ARCS  16
#define CHAIN 3
#define START_STATE 0
#define WAVE 64
#define WAVES_PER_BLOCK 4
#define BLOCK (WAVE * WAVES_PER_BLOCK)
#define NCHUNK (VOCAB / (WAVE * 4))   // 4 x 16B chunks per thread

typedef float f32x4 __attribute__((ext_vector_type(4)));
typedef int   i32x4 __attribute__((ext_vector_type(4)));

// 4 waves/block, one hypothesis per wave, wave-PRIVATE 8KB LDS overlay table
// -> no barriers, no fences, single HBM write stream (no scatter double-write).
// Priority: three LDS commit rounds in reverse order (level 2 -> 1 -> 0);
// same-wave LDS ops are in-order, so level 0 (highest n-gram order) wins.
__global__ __launch_bounds__(BLOCK, 5) void ngram_advance_kernel(
    const float* __restrict__ arcs_weights,
    const float* __restrict__ backoff_weights,
    const int*   __restrict__ ilabels,
    const int*   __restrict__ to_states,
    const int*   __restrict__ backoff_to,
    const int*   __restrict__ state_start,
    const int*   __restrict__ state_end,
    const int*   __restrict__ states,
    float*       __restrict__ out_scores,   // [B, V]
    float*       __restrict__ out_next,     // [B, V] state ids as f32
    int B)
{
    __shared__ int   s_next[WAVES_PER_BLOCK][VOCAB];   // -1 = not found
    __shared__ float s_sc  [WAVES_PER_BLOCK][VOCAB];

    const int lane = threadIdx.x & (WAVE - 1);
    const int wid  = __builtin_amdgcn_readfirstlane(threadIdx.x >> 6);
    const int b    = blockIdx.x * WAVES_PER_BLOCK + wid;
    if (b >= B) return;

    int*   __restrict__ ovn = s_next[wid];
    float* __restrict__ ovs = s_sc[wid];

    // ---- 1. Kick off the dependent chain immediately (scalar load). ----
    int cur = states[b];

    // ---- 2. Sentinel-init own overlay table + prefetch dense tables to
    // registers; all of this hides under the chain-walk latency. ----
    #pragma unroll
    for (int i = 0; i < NCHUNK; ++i)
        *(i32x4*)&ovn[(lane + i * WAVE) * 4] = (i32x4){-1, -1, -1, -1};

    f32x4 rn[NCHUNK], dw[NCHUNK];
    #pragma unroll
    for (int i = 0; i < NCHUNK; ++i) {
        const int v = (lane + i * WAVE) * 4;
        const i32x4 dn = *(const i32x4*)&to_states[v];     // L1-hot
        rn[i].x = (float)dn.x; rn[i].y = (float)dn.y;
        rn[i].z = (float)dn.z; rn[i].w = (float)dn.w;
        dw[i] = *(const f32x4*)&arcs_weights[v];           // L1-hot
    }

    // ---- 3. Chain walk, branchless (backoff_weights[0]==0, backoff_to[0]==0:
    // START self-loops at zero cost). Wave-uniform -> scalarized. ----
    float acc = 0.0f;
    const int   cs0 = cur;  const float ca0 = acc;
    acc += backoff_weights[cur];  cur = backoff_to[cur];
    const int   cs1 = cur;  const float ca1 = acc;
    acc += backoff_weights[cur];  cur = backoff_to[cur];
    const int   cs2 = cur;  const float ca2 = acc;
    acc += backoff_weights[cur];
    const float accf = acc;

    // ---- 4. Arc fetch: lanes 0..47, level = lane>>4, arc = lane&15. ----
    const int level = lane >> 4;
    const int arc   = lane & (ARCS - 1);
    int   lab = -1, ns = 0;
    float sc  = 0.0f;
    bool  ok  = false;
    if (lane < CHAIN * ARCS) {
        const int   s    = (level == 0) ? cs0 : (level == 1) ? cs1 : cs2;
        const float cacc = (level == 0) ? ca0 : (level == 1) ? ca1 : ca2;
        if (s != START_STATE) {
            const int idx = state_start[s] + arc;
            if (idx < state_end[s]) {
                lab = ilabels[idx];
                sc  = cacc + arcs_weights[idx];
                ns  = to_states[idx];
                ok  = true;
            }
        }
    }

    // ---- 5. Ordered overlay commits: level 2, then 1, then 0. Same-wave
    // LDS ops execute in order; sched_barrier(0) prevents any compiler
    // motion across the levels. Level 0 (highest order) commits last = wins
    // (matches the reference's first-write-wins found_e semantics). ----
    if (ok && level == 2) { ovs[lab] = sc; ovn[lab] = ns; }
    __builtin_amdgcn_sched_barrier(0);
    if (ok && level == 1) { ovs[lab] = sc; ovn[lab] = ns; }
    __builtin_amdgcn_sched_barrier(0);
    if (ok && level == 0) { ovs[lab] = sc; ovn[lab] = ns; }
    __builtin_amdgcn_sched_barrier(0);

    // ---- 6. Merge + single coalesced store pass. ----
    float* __restrict__ so = out_scores + (size_t)b * VOCAB;
    float* __restrict__ no = out_next   + (size_t)b * VOCAB;
    #pragma unroll
    for (int i = 0; i < NCHUNK; ++i) {
        const int v = (lane + i * WAVE) * 4;
        const i32x4 on = *(const i32x4*)&ovn[v];
        const f32x4 os = *(const f32x4*)&ovs[v];
        f32x4 rs, rx;
        rs.x = (on.x >= 0) ? os.x : accf + dw[i].x;
        rs.y = (on.y >= 0) ? os.y : accf + dw[i].y;
        rs.z = (on.z >= 0) ? os.z : accf + dw[i].z;
        rs.w = (on.w >= 0) ? os.w : accf + dw[i].w;
        rx.x = (on.x >= 0) ? (float)on.x : rn[i].x;
        rx.y = (on.y >= 0) ? (float)on.y : rn[i].y;
        rx.z = (on.z >= 0) ? (float)on.z : rn[i].z;
        rx.w = (on.w >= 0) ? (float)on.w : rn[i].w;
        *(f32x4*)&so[v] = rs;
        *(f32x4*)&no[v] = rx;
    }
}

extern "C" void kernel_launch(void* const* d_in, const int* in_sizes, int n_in,
                              void* d_out, int out_size, void* d_ws, size_t ws_size,
                              hipStream_t stream) {
    const float* arcs_weights    = (const float*)d_in[0];
    const float* backoff_weights = (const float*)d_in[1];
    const int*   ilabels         = (const int*)d_in[2];
    const int*   to_states       = (const int*)d_in[3];
    const int*   backoff_to      = (const int*)d_in[4];
    const int*   state_start     = (const int*)d_in[5];
    const int*   state_end       = (const int*)d_in[6];
    const int*   states          = (const int*)d_in[7];

    const int B = in_sizes[7];                           // 8192 hypotheses
    float* out_scores = (float*)d_out;                   // first B*V floats
    float* out_next   = out_scores + (size_t)B * VOCAB;  // second B*V

    const int grid = (B + WAVES_PER_BLOCK - 1) / WAVES_PER_BLOCK;
    ngram_advance_kernel<<<grid, BLOCK, 0, stream>>>(
        arcs_weights, backoff_weights, ilabels, to_states, backoff_to,
        state_start, state_end, states, out_scores, out_next, B);
}

// Round 8
// 19.379 us; speedup vs baseline: 1.3969x; 1.0087x over previous
//
#include <hip/hip_runtime.h>

#define VOCAB 1024
#define ARCS  16
#define CHAIN 3
#define START_STATE 0
#define WAVE 64
#define WAVES_PER_BLOCK 4
#define BLOCK (WAVE * WAVES_PER_BLOCK)
#define NCHUNK (VOCAB / (WAVE * 4))   // 4 chunks of 4 labels per thread

typedef float f32x4 __attribute__((ext_vector_type(4)));
typedef int   i32x4 __attribute__((ext_vector_type(4)));

// 4 waves/block, one hypothesis per wave. LDS = 1KB/wave who-table only
// (u8 owner lane per label, 0xFF = none); overlay VALUES stay in the owning
// lane's registers and are pulled cross-lane with ds_bpermute at merge time.
// -> 4KB LDS/block, occupancy wave-slot-capped at 32 waves/CU.
// Priority: u8 commits in order level 2 -> 1 -> 0 (same-wave LDS ops are
// program-ordered; level 0 = highest n-gram order commits last and wins).
__global__ __launch_bounds__(BLOCK, 8) void ngram_advance_kernel(
    const float* __restrict__ arcs_weights,
    const float* __restrict__ backoff_weights,
    const int*   __restrict__ ilabels,
    const int*   __restrict__ to_states,
    const int*   __restrict__ backoff_to,
    const int*   __restrict__ state_start,
    const int*   __restrict__ state_end,
    const int*   __restrict__ states,
    float*       __restrict__ out_scores,   // [B, V]
    float*       __restrict__ out_next,     // [B, V] state ids as f32
    int B)
{
    __shared__ unsigned char s_who[WAVES_PER_BLOCK][VOCAB];  // 4 KB total

    const int lane = threadIdx.x & (WAVE - 1);
    const int wid  = __builtin_amdgcn_readfirstlane(threadIdx.x >> 6);
    const int b    = blockIdx.x * WAVES_PER_BLOCK + wid;
    if (b >= B) return;

    unsigned char* __restrict__ who = s_who[wid];

    // ---- 1. Kick off the dependent chain immediately (uniform -> s_load).
    int cur = states[b];

    // ---- 2. Sentinel-init own 1KB who-table: one ds_write_b128 per lane.
    *(i32x4*)&who[lane * 16] = (i32x4){-1, -1, -1, -1};

    // ---- 3. Chain walk, branchless (backoff_weights[0]==0, backoff_to[0]==0:
    // START self-loops at zero cost). Wave-uniform -> scalarized.
    float acc = 0.0f;
    const int   cs0 = cur;  const float ca0 = acc;
    acc += backoff_weights[cur];  cur = backoff_to[cur];
    const int   cs1 = cur;  const float ca1 = acc;
    acc += backoff_weights[cur];  cur = backoff_to[cur];
    const int   cs2 = cur;  const float ca2 = acc;
    acc += backoff_weights[cur];
    const float accf = acc;

    // ---- 4. Arc fetch: lanes 0..47, level = lane>>4, arc = lane&15. ----
    const int level = lane >> 4;
    const int arc   = lane & (ARCS - 1);
    int   lab = -1;
    float sc  = 0.0f, fns = 0.0f;
    bool  ok  = false;
    if (lane < CHAIN * ARCS) {
        const int   s    = (level == 0) ? cs0 : (level == 1) ? cs1 : cs2;
        const float cacc = (level == 0) ? ca0 : (level == 1) ? ca1 : ca2;
        if (s != START_STATE) {
            const int idx = state_start[s] + arc;
            if (idx < state_end[s]) {
                lab = ilabels[idx];
                sc  = cacc + arcs_weights[idx];
                fns = (float)to_states[idx];
                ok  = true;
            }
        }
    }

    // ---- 5. Ordered who-commits: level 2, then 1, then 0. Same-wave LDS
    // ops are in-order; sched_barrier(0) pins the three rounds. Within a
    // level, labels are unique (builder sorts unique ilabels per state).
    if (ok && level == 2) who[lab] = (unsigned char)lane;
    __builtin_amdgcn_sched_barrier(0);
    if (ok && level == 1) who[lab] = (unsigned char)lane;
    __builtin_amdgcn_sched_barrier(0);
    if (ok && level == 0) who[lab] = (unsigned char)lane;
    __builtin_amdgcn_sched_barrier(0);

    // ---- 6. Merge: who-byte -> bpermute value from owning lane; dense
    // defaults loaded in-loop (L1-hot tables). Single coalesced write pass.
    float* __restrict__ so = out_scores + (size_t)b * VOCAB;
    float* __restrict__ no = out_next   + (size_t)b * VOCAB;
    const int sci = __float_as_int(sc);
    const int nsi = __float_as_int(fns);
    #pragma unroll
    for (int i = 0; i < NCHUNK; ++i) {
        const int v = (lane + i * WAVE) * 4;
        const unsigned w4 = *(const unsigned*)&who[v];
        const f32x4 dwv = *(const f32x4*)&arcs_weights[v];  // L1-hot
        const i32x4 dnv = *(const i32x4*)&to_states[v];     // L1-hot
        f32x4 rs, rx;
        #pragma unroll
        for (int j = 0; j < 4; ++j) {
            const unsigned wb = (w4 >> (8 * j)) & 0xFFu;
            const float scv = __int_as_float(
                __builtin_amdgcn_ds_bpermute((int)(wb << 2), sci));
            const float nsv = __int_as_float(
                __builtin_amdgcn_ds_bpermute((int)(wb << 2), nsi));
            const bool hit = (wb != 0xFFu);
            rs[j] = hit ? scv : accf + dwv[j];
            rx[j] = hit ? nsv : (float)dnv[j];
        }
        *(f32x4*)&so[v] = rs;
        *(f32x4*)&no[v] = rx;
    }
}

extern "C" void kernel_launch(void* const* d_in, const int* in_sizes, int n_in,
                              void* d_out, int out_size, void* d_ws, size_t ws_size,
                              hipStream_t stream) {
    const float* arcs_weights    = (const float*)d_in[0];
    const float* backoff_weights = (const float*)d_in[1];
    const int*   ilabels         = (const int*)d_in[2];
    const int*   to_states       = (const int*)d_in[3];
    const int*   backoff_to      = (const int*)d_in[4];
    const int*   state_start     = (const int*)d_in[5];
    const int*   state_end       = (const int*)d_in[6];
    const int*   states          = (const int*)d_in[7];

    const int B = in_sizes[7];                           // 8192 hypotheses
    float* out_scores = (float*)d_out;                   // first B*V floats
    float* out_next   = out_scores + (size_t)B * VOCAB;  // second B*V

    const int grid = (B + WAVES_PER_BLOCK - 1) / WAVES_PER_BLOCK;
    ngram_advance_kernel<<<grid, BLOCK, 0, stream>>>(
        arcs_weights, backoff_weights, ilabels, to_states, backoff_to,
        state_start, state_end, states, out_scores, out_next, B);
}